// Round 2
// baseline (110840.454 us; speedup 1.0000x reference)
//
#include <hip/hip_runtime.h>
#include <hip/hip_bf16.h>
#include <hip/hip_cooperative_groups.h>
#include <stdint.h>

namespace cg = cooperative_groups;

// SelectionLstm: T=2000, B=64, H=512. Fully-fused recurrence:
// gates_t = [x_t, h_{t-1}] @ [W_hat | U_hat]^T + b   (bf16 MFMA, f32 accum)
// 256 blocks = 4 batch-groups x 64 col-blocks (8 h-cols / 32 gate-rows each).
// [W|U] slice persistent in LDS (64KB, XOR-swizzled). Per-step h exchange via
// small global buffer + cooperative grid.sync() (safe cross-XCD ordering).
// Workspace need: ~4.3MB only (no big xW precompute -> no OOB risk).

#define T_STEPS 2000

typedef __attribute__((ext_vector_type(8))) short short8;
typedef __attribute__((ext_vector_type(4))) float floatx4;

// ---- workspace layout (bytes) ----
#define OFF_HEX   0ull                         // 2*64*512 ushort = 131072 B
#define OFF_WHAT  131072ull                    // 2048*512*2 = 2 MB
#define OFF_UHAT  (OFF_WHAT + 2097152ull)      // 2 MB
#define WS_NEED   (OFF_UHAT + 2097152ull)      // ~4.3 MB

#define SMEM_FUSED (65536 + 32768 + 9216)      // WU + A + partials = 107520 B

__device__ __forceinline__ float sigf(float x){ return 1.0f/(1.0f + expf(-x)); }
__device__ __forceinline__ float gate_s(float a){
  float s = sigf(a)*1.2f - 0.1f;               // (ZETA-GAMMA)=1.2, GAMMA=-0.1
  return fminf(1.0f, fmaxf(0.0f, s));
}
__device__ __forceinline__ uint16_t f2bf(float f){
  union { float f; uint32_t u; } v; v.f = f;
  uint32_t u = v.u;
  return (uint16_t)((u + 0x7fffu + ((u>>16)&1u)) >> 16);   // RNE
}

// ---------------- prep: masked weights (bf16) ----------------
__global__ __launch_bounds__(512) void prep_weights(
    const float* __restrict__ W, const float* __restrict__ U,
    const float* __restrict__ la, uint16_t* __restrict__ what,
    uint16_t* __restrict__ uhat)
{
  int r = blockIdx.x;       // gate row 0..2047
  int c = threadIdx.x;      // col 0..511
  float sc = gate_s(la[c]);
  float sr = gate_s(la[r & 511]);
  size_t idx = (size_t)r*512 + c;
  what[idx] = f2bf(W[idx]*sc);        // W_hat = W * s[col]
  uhat[idx] = f2bf(U[idx]*sr*sc);     // U_hat = U * s[row%512] * s[col]
}

// ---------------- fused persistent recurrence ----------------
__global__ __launch_bounds__(256, 1) void lstm_fused(
    const uint16_t* __restrict__ what,
    const uint16_t* __restrict__ uhat,
    const float* __restrict__ bias,
    const float* __restrict__ x,
    uint16_t* __restrict__ hex,
    float* __restrict__ out)
{
  extern __shared__ char smem[];
  char*  WU = smem;                    // [32 rows][2048B] bf16, XOR-swizzled
  char*  AL = smem + 65536;            // [16 rows][2048B] bf16 ([x | h]), swizzled
  float* GP = (float*)(smem + 65536 + 32768);  // [4 waves][16 m][36] partials

  cg::grid_group grid = cg::this_grid();

  const int tid  = threadIdx.x;
  const int lane = tid & 63;
  const int wave = tid >> 6;
  const int bid  = blockIdx.x;
  const int g    = bid >> 6;           // batch group 0..3 (rows g*16..g*16+15)
  const int cblk = bid & 63;           // col block 0..63
  const int c0   = cblk * 8;           // owned h-cols [c0, c0+8)

  // ---- zero A (h-part must start as h0 = 0) ----
  #pragma unroll
  for (int i = 0; i < 8; ++i){
    uint4 z = make_uint4(0u,0u,0u,0u);
    *(uint4*)(AL + (i*256 + tid)*16) = z;
  }

  // ---- stage [W|U] slice into LDS (swizzled). local row rl = q*8+j ----
  #pragma unroll
  for (int i = 0; i < 16; ++i){
    int f4  = i*256 + tid;             // uint4 index over [32 rows][128]
    int rl  = f4 >> 7;                 // local row
    int k16 = f4 & 127;                // 16B chunk within 2048B row
    int q = rl >> 3, j = rl & 7;
    int rowg = q*512 + c0 + j;         // global gate row
    int ku0 = k16*4;                   // uint index within row (0..511)
    uint4 v;
    if (ku0 < 256) v = *(const uint4*)((const uint32_t*)what + (size_t)rowg*256 + ku0);
    else           v = *(const uint4*)((const uint32_t*)uhat + (size_t)rowg*256 + (ku0-256));
    *(uint4*)(WU + rl*2048 + ((k16*16) ^ ((rl&7)<<4))) = v;
  }

  // ---- elementwise role (threads 0..127): batch tb, local col j ----
  const int tb = tid >> 3;
  const int j  = tid & 7;
  float bsv[4];
  #pragma unroll
  for (int q = 0; q < 4; ++q) bsv[q] = bias[q*512 + c0 + j];
  float cst = 0.0f;

  // ---- x prefetch machinery: 16 batch rows x 512 cols f32 -> bf16 regs ----
  uint32_t xr[16];
  auto prefx = [&](int t){
    #pragma unroll
    for (int i = 0; i < 8; ++i){
      int f4 = i*256 + tid;            // float4 idx over [16][128]
      int rl = f4 >> 7;
      int kc = (f4 & 127)*4;
      float4 v = *(const float4*)(x + ((size_t)t*64 + g*16 + rl)*512 + kc);
      xr[2*i]   = (uint32_t)f2bf(v.x) | ((uint32_t)f2bf(v.y) << 16);
      xr[2*i+1] = (uint32_t)f2bf(v.z) | ((uint32_t)f2bf(v.w) << 16);
    }
  };
  auto writex = [&](){
    #pragma unroll
    for (int i = 0; i < 8; ++i){
      int f4 = i*256 + tid;
      int rl = f4 >> 7;
      int kb = (f4 & 127)*8;           // byte offset of 4 bf16 within x-part
      uint2 w; w.x = xr[2*i]; w.y = xr[2*i+1];
      *(uint2*)(AL + rl*2048 + (kb ^ ((rl&7)<<4))) = w;
    }
  };

  __syncthreads();         // zero-A / WU-stage complete
  prefx(0);
  writex();                // x-part for t=0
  __syncthreads();

  const int arow = lane & 15;
  const int aswz = (arow & 7) << 4;
  const int q16  = (lane >> 4) << 4;

  for (int t = 0; t < T_STEPS; ++t){
    // ---- gates partial: wave covers K-range [wave*256, wave*256+256) ----
    floatx4 a0 = (floatx4){0.f,0.f,0.f,0.f};
    floatx4 a1 = (floatx4){0.f,0.f,0.f,0.f};
    #pragma unroll
    for (int kt = 0; kt < 8; ++kt){
      int kb = wave*512 + kt*64 + q16;
      short8 av = *(const short8*)(AL + arow*2048 + (kb ^ aswz));
      short8 b0 = *(const short8*)(WU + arow*2048 + (kb ^ aswz));
      short8 b1 = *(const short8*)(WU + (16+arow)*2048 + (kb ^ aswz));
      a0 = __builtin_amdgcn_mfma_f32_16x16x32_bf16(av, b0, a0, 0,0,0);
      a1 = __builtin_amdgcn_mfma_f32_16x16x32_bf16(av, b1, a1, 0,0,0);
    }
    {
      int m0 = (lane >> 4) * 4;
      int n  = lane & 15;
      #pragma unroll
      for (int r = 0; r < 4; ++r){
        GP[(wave*16 + m0 + r)*36 + n]      = a0[r];
        GP[(wave*16 + m0 + r)*36 + n + 16] = a1[r];
      }
    }
    __syncthreads();

    // ---- elementwise cell (c persistent in regs) ----
    if (tid < 128){
      float pre[4];
      #pragma unroll
      for (int q = 0; q < 4; ++q){
        float s = bsv[q];
        #pragma unroll
        for (int w = 0; w < 4; ++w) s += GP[(w*16 + tb)*36 + q*8 + j];
        pre[q] = s;
      }
      float iv = sigf(pre[0]);
      float fv = sigf(pre[1]);
      float gv = tanhf(pre[2]);
      float ov = sigf(pre[3]);
      cst = fv*cst + iv*gv;
      float hv = ov * tanhf(cst);
      out[((size_t)t*64 + g*16 + tb)*512 + c0 + j] = hv;
      hex[((size_t)(t&1))*32768 + (size_t)(g*16 + tb)*512 + c0 + j] = f2bf(hv);
    }

    // prefetch next x while waiting at the barrier
    int tn = (t+1 < T_STEPS) ? (t+1) : (T_STEPS-1);
    prefx(tn);

    __threadfence();
    grid.sync();

    // ---- restage full group h into A h-part ----
    {
      const uint32_t* hb = (const uint32_t*)hex + (size_t)(t&1)*16384;
      #pragma unroll
      for (int i = 0; i < 4; ++i){
        int f4 = i*256 + tid;          // uint4 idx over [16 rows][64]
        int rl = f4 >> 6;
        int kp = (f4 & 63)*4;          // uint offset within row (256 uints)
        uint4 v = *(const uint4*)(hb + (size_t)(g*16 + rl)*256 + kp);
        *(uint4*)(AL + rl*2048 + ((1024 + kp*4) ^ ((rl&7)<<4))) = v;
      }
    }
    writex();                          // x-part for t+1
    __syncthreads();
  }
}

extern "C" void kernel_launch(void* const* d_in, const int* in_sizes, int n_in,
                              void* d_out, int out_size, void* d_ws, size_t ws_size,
                              hipStream_t stream) {
  (void)in_sizes; (void)n_in; (void)out_size; (void)ws_size;
  const float* x    = (const float*)d_in[0];
  const float* W    = (const float*)d_in[1];
  const float* U    = (const float*)d_in[2];
  const float* bias = (const float*)d_in[3];
  const float* la   = (const float*)d_in[4];
  float* out = (float*)d_out;
  char*  ws  = (char*)d_ws;

  uint16_t* hex  = (uint16_t*)(ws + OFF_HEX);
  uint16_t* what = (uint16_t*)(ws + OFF_WHAT);
  uint16_t* uhat = (uint16_t*)(ws + OFF_UHAT);

  hipFuncSetAttribute((const void*)lstm_fused,
                      hipFuncAttributeMaxDynamicSharedMemorySize, SMEM_FUSED);

  prep_weights<<<2048, 512, 0, stream>>>(W, U, la, what, uhat);

  void* args[] = { (void*)&what, (void*)&uhat, (void*)&bias,
                   (void*)&x, (void*)&hex, (void*)&out };
  hipLaunchCooperativeKernel((const void*)lstm_fused, dim3(256), dim3(256),
                             args, SMEM_FUSED, stream);
}

// Round 7
// 36635.641 us; speedup vs baseline: 3.0255x; 3.0255x over previous
//
#include <hip/hip_runtime.h>
#include <hip/hip_bf16.h>
#include <hip/hip_cooperative_groups.h>
#include <stdint.h>

namespace cg = cooperative_groups;

// SelectionLstm: T=2000, B=64, H=512.
// Round 7: all custom spin/atomic sync REMOVED (3 container deaths + 1
// stale-data failure). Only proven primitives: grid.sync + plain st/ld +
// threadfence (R2 recipe). Cost lever: 64 cooperative blocks instead of 256.
//  - gemm_xw: xW = x @ W_hat^T precomputed (bf16, 524MB in ws), guarded by
//    ws_size; fallback = the exact R2-passing 256-block fused kernel.
//  - lstm_rec64: 64 blocks = 4 groups x 16 cblk; U-slice (128x512 bf16 =
//    128KB) persistent in LDS; per-step h exchange via plain stores ->
//    threadfence -> grid.sync -> plain loads (double-buffered hex).

#define T_STEPS 2000

typedef __attribute__((ext_vector_type(8))) short short8;
typedef __attribute__((ext_vector_type(4))) float floatx4;

// ---- workspace layout (bytes) ----
#define OFF_HEX   0ull                          // 2*64*512 ushort = 131072
#define OFF_WHAT  131072ull                     // 2048*512*2 = 2 MB
#define OFF_UHAT  (OFF_WHAT + 2097152ull)       // 2 MB
#define OFF_XW    (OFF_UHAT + 2097152ull)       // 128000*2048*2 = 524288000
#define WS_NEED_BIG (OFF_XW + 524288000ull)     // ~529 MB

#define SMEM_REC64 (131072 + 16384 + 8448)      // U + A(h) + G = 155904
#define SMEM_FUSED (65536 + 32768 + 9216)       // fallback (R2) = 107520

__device__ __forceinline__ float sigf(float x){ return 1.0f/(1.0f + expf(-x)); }
__device__ __forceinline__ float gate_s(float a){
  float s = sigf(a)*1.2f - 0.1f;                // (ZETA-GAMMA)=1.2, GAMMA=-0.1
  return fminf(1.0f, fmaxf(0.0f, s));
}
__device__ __forceinline__ uint16_t f2bf(float f){
  union { float f; uint32_t u; } v; v.f = f;
  uint32_t u = v.u;
  return (uint16_t)((u + 0x7fffu + ((u>>16)&1u)) >> 16);   // RNE
}
__device__ __forceinline__ float bf2f(uint16_t b){
  union { uint32_t u; float f; } v; v.u = ((uint32_t)b)<<16; return v.f;
}

// ---------------- prep: masked weights (bf16) ----------------
__global__ __launch_bounds__(512) void prep_weights(
    const float* __restrict__ W, const float* __restrict__ U,
    const float* __restrict__ la, uint16_t* __restrict__ what,
    uint16_t* __restrict__ uhat)
{
  int r = blockIdx.x;       // gate row 0..2047
  int c = threadIdx.x;      // col 0..511
  float sc = gate_s(la[c]);
  float sr = gate_s(la[r & 511]);
  size_t idx = (size_t)r*512 + c;
  what[idx] = f2bf(W[idx]*sc);        // W_hat = W * s[col]
  uhat[idx] = f2bf(U[idx]*sr*sc);     // U_hat = U * s[row%512] * s[col]
}

// ---------------- GEMM: xw[m][n] = sum_k x[m][k]*W_hat[n][k] ----------------
// 128x128 tile, BK=64, 4 waves (64x64 quadrants), XOR-swizzled LDS.
// Fragment math identical to the R2-verified lstm MFMA pattern.
__global__ __launch_bounds__(256) void gemm_xw(
    const float* __restrict__ x,      // [128000][512] f32 (converted in-stage)
    const uint16_t* __restrict__ Bw,  // [2048][512] bf16 (W_hat)
    uint16_t* __restrict__ xw)        // [128000][2048] bf16
{
  __shared__ uint16_t As[128*64];
  __shared__ uint16_t Bs[128*64];
  const int tid  = threadIdx.x;
  const int lane = tid & 63;
  const int wave = tid >> 6;
  const int wr = wave >> 1, wc = wave & 1;
  const int bm = blockIdx.x, bn = blockIdx.y;

  floatx4 acc[4][4];
  #pragma unroll
  for (int i=0;i<4;++i)
    #pragma unroll
    for (int jq=0;jq<4;++jq) acc[i][jq] = (floatx4){0.f,0.f,0.f,0.f};

  const int arow = tid >> 4;          // A-stage: 16 rows/iter, f32
  const int af4  = tid & 15;          // float4 index within 64-f32 row chunk
  const int brow = tid >> 3;          // B-stage: 32 rows/iter, bf16
  const int bch  = (tid & 7) * 16;    // byte chunk within 128B row

  for (int kt = 0; kt < 8; ++kt){
    // stage A (f32 -> bf16, swizzled)
    #pragma unroll
    for (int is = 0; is < 8; ++is){
      int row = is*16 + arow;
      float4 v = *(const float4*)(x + (size_t)(bm*128 + row)*512 + kt*64 + af4*4);
      uint2 p;
      p.x = (uint32_t)f2bf(v.x) | ((uint32_t)f2bf(v.y)<<16);
      p.y = (uint32_t)f2bf(v.z) | ((uint32_t)f2bf(v.w)<<16);
      *(uint2*)((char*)As + row*128 + ((af4*8) ^ ((row&7)<<4))) = p;
    }
    // stage B (bf16, swizzled)
    #pragma unroll
    for (int is = 0; is < 4; ++is){
      int row = is*32 + brow;
      uint4 v = *(const uint4*)((const char*)Bw + ((size_t)(bn*128 + row)*512 + kt*64)*2 + bch);
      *(uint4*)((char*)Bs + row*128 + (bch ^ ((row&7)<<4))) = v;
    }
    __syncthreads();
    #pragma unroll
    for (int ks = 0; ks < 2; ++ks){
      const int q16 = (lane >> 4) << 4;
      short8 af[4], bfm[4];
      #pragma unroll
      for (int mi = 0; mi < 4; ++mi){
        int row = wr*64 + mi*16 + (lane&15);
        af[mi] = *(const short8*)((const char*)As + row*128 + ((ks*64 + q16) ^ ((row&7)<<4)));
      }
      #pragma unroll
      for (int ni = 0; ni < 4; ++ni){
        int row = wc*64 + ni*16 + (lane&15);
        bfm[ni] = *(const short8*)((const char*)Bs + row*128 + ((ks*64 + q16) ^ ((row&7)<<4)));
      }
      #pragma unroll
      for (int mi = 0; mi < 4; ++mi)
        #pragma unroll
        for (int ni = 0; ni < 4; ++ni)
          acc[mi][ni] = __builtin_amdgcn_mfma_f32_16x16x32_bf16(af[mi], bfm[ni], acc[mi][ni], 0,0,0);
    }
    __syncthreads();
  }
  // epilogue: C[m][n], m = x-row, n = gate-row (col=lane&15, row=(lane>>4)*4+r)
  #pragma unroll
  for (int mi = 0; mi < 4; ++mi){
    #pragma unroll
    for (int ni = 0; ni < 4; ++ni){
      #pragma unroll
      for (int r = 0; r < 4; ++r){
        size_t m = (size_t)bm*128 + wr*64 + mi*16 + ((lane>>4)*4 + r);
        int    n = bn*128 + wc*64 + ni*16 + (lane&15);
        xw[m*2048 + n] = f2bf(acc[mi][ni][r]);
      }
    }
  }
}

// ---------------- 64-block recurrence (grid.sync) ----------------
// 64 blocks = 4 groups(g) x 16 cblk. Block owns h-cols [32*cblk,32*cblk+32)
// -> 128 gate rows. Wave w == gate q=w (N-split, full K=512, no partials).
__global__ __launch_bounds__(256, 1) void lstm_rec64(
    const uint16_t* __restrict__ uhat,
    const float* __restrict__ bias,
    const uint16_t* __restrict__ xw,
    uint16_t* __restrict__ hex,
    float* __restrict__ out)
{
  extern __shared__ char smem[];
  char*  UL = smem;                        // [128 rows][1024B] swizzled
  char*  AL = smem + 131072;               // [16 rows][1024B] (h) swizzled
  float* G  = (float*)(smem + 131072 + 16384);  // [16][132] f32 gates

  cg::grid_group grid = cg::this_grid();

  const int tid  = threadIdx.x;
  const int lane = tid & 63;
  const int wave = tid >> 6;
  const int bid  = blockIdx.x;
  const int g    = bid >> 4;               // batch group 0..3
  const int cblk = bid & 15;               // 0..15
  const int c0   = cblk * 32;              // owned h-cols [c0, c0+32)

  // ---- stage U slice (128 rows x 512 bf16, swizzled). rl = q*32+jj ----
  for (int i = 0; i < 32; ++i){
    int ch  = i*256 + tid;                 // uint4 chunk 0..8191
    int rl  = ch >> 6;
    int k16 = ch & 63;
    int q = rl >> 5, jj = rl & 31;
    uint4 v = *(const uint4*)((const char*)uhat + (size_t)(q*512 + c0 + jj)*1024 + k16*16);
    *(uint4*)(UL + rl*1024 + ((k16*16) ^ ((rl&7)<<4))) = v;
  }
  // ---- zero A (h0 = 0; zeros are swizzle-invariant) ----
  #pragma unroll
  for (int i = 0; i < 4; ++i){
    uint4 z = make_uint4(0u,0u,0u,0u);
    *(uint4*)(AL + (i*256 + tid)*16) = z;
  }

  // elementwise role: batch tb, cols c0+j and c0+16+j
  const int tb = tid >> 4;
  const int j  = tid & 15;
  float bsv[4][2];
  #pragma unroll
  for (int q = 0; q < 4; ++q){
    bsv[q][0] = bias[q*512 + c0 + j];
    bsv[q][1] = bias[q*512 + c0 + 16 + j];
  }
  float cs0 = 0.f, cs1 = 0.f;

  // MFMA roles
  const int arow = lane & 15;
  const int r0 = 32*wave + (lane & 15);
  const int r1 = r0 + 16;
  const int aswz = (arow & 7) << 4;
  const int r0s = (r0 & 7) << 4;
  const int r1s = (r1 & 7) << 4;
  const int q16 = (lane >> 4) << 4;

  __syncthreads();

  for (int t = 0; t < T_STEPS; ++t){
    // prefetch this step's xW slice (hidden under MFMA)
    float xg[4][2];
    {
      size_t xb = ((size_t)t*64 + g*16 + tb)*2048 + c0 + j;
      #pragma unroll
      for (int q = 0; q < 4; ++q){
        xg[q][0] = bf2f(xw[xb + q*512]);
        xg[q][1] = bf2f(xw[xb + q*512 + 16]);
      }
    }
    // gates = h @ U_slice^T : wave w covers gate rows [32w, 32w+32), K=512
    floatx4 a0 = (floatx4){0.f,0.f,0.f,0.f};
    floatx4 a1 = (floatx4){0.f,0.f,0.f,0.f};
    #pragma unroll
    for (int kt = 0; kt < 16; ++kt){
      int kb = kt*64 + q16;
      short8 av = *(const short8*)(AL + arow*1024 + (kb ^ aswz));
      short8 b0 = *(const short8*)(UL + r0*1024 + (kb ^ r0s));
      short8 b1 = *(const short8*)(UL + r1*1024 + (kb ^ r1s));
      a0 = __builtin_amdgcn_mfma_f32_16x16x32_bf16(av, b0, a0, 0,0,0);
      a1 = __builtin_amdgcn_mfma_f32_16x16x32_bf16(av, b1, a1, 0,0,0);
    }
    {
      int m0 = (lane >> 4) * 4;
      int n  = lane & 15;
      #pragma unroll
      for (int r = 0; r < 4; ++r){
        G[(m0+r)*132 + 32*wave + n]      = a0[r];
        G[(m0+r)*132 + 32*wave + 16 + n] = a1[r];
      }
    }
    __syncthreads();

    // ---- elementwise cell (c in regs), 2 cells/thread ----
    {
      float p0[4], p1[4];
      #pragma unroll
      for (int q = 0; q < 4; ++q){
        p0[q] = G[tb*132 + q*32 + j]      + xg[q][0] + bsv[q][0];
        p1[q] = G[tb*132 + q*32 + 16 + j] + xg[q][1] + bsv[q][1];
      }
      float i0 = sigf(p0[0]), f0 = sigf(p0[1]), g0 = tanhf(p0[2]), o0 = sigf(p0[3]);
      float i1 = sigf(p1[0]), f1 = sigf(p1[1]), g1 = tanhf(p1[2]), o1 = sigf(p1[3]);
      cs0 = f0*cs0 + i0*g0;
      cs1 = f1*cs1 + i1*g1;
      float h0 = o0 * tanhf(cs0);
      float h1 = o1 * tanhf(cs1);
      size_t ob = ((size_t)t*64 + g*16 + tb)*512 + c0 + j;
      out[ob]      = h0;
      out[ob + 16] = h1;
      int buf = t & 1;
      size_t hx = (size_t)buf*32768 + (size_t)(g*16 + tb)*512 + c0 + j;
      hex[hx]      = f2bf(h0);     // plain stores; grid.sync fences publish them
      hex[hx + 16] = f2bf(h1);
    }

    __threadfence();
    grid.sync();

    // ---- restage full group h (16x512 bf16) into A ----
    {
      const uint4* hb = (const uint4*)(hex + (size_t)(t&1)*32768);
      #pragma unroll
      for (int i = 0; i < 4; ++i){
        int ch  = i*256 + tid;             // 0..1023 over [16 rows][64 chunks]
        int rh  = ch >> 6;
        int k16 = ch & 63;
        uint4 v = hb[(g*16 + rh)*64 + k16];
        *(uint4*)(AL + rh*1024 + ((k16*16) ^ ((rh&7)<<4))) = v;
      }
    }
    __syncthreads();
  }
}

// ---------------- fallback: exact R2-passing 256-block fused kernel ----------------
__global__ __launch_bounds__(256, 1) void lstm_fused(
    const uint16_t* __restrict__ what,
    const uint16_t* __restrict__ uhat,
    const float* __restrict__ bias,
    const float* __restrict__ x,
    uint16_t* __restrict__ hex,
    float* __restrict__ out)
{
  extern __shared__ char smem[];
  char*  WU = smem;
  char*  AL = smem + 65536;
  float* GP = (float*)(smem + 65536 + 32768);

  cg::grid_group grid = cg::this_grid();

  const int tid  = threadIdx.x;
  const int lane = tid & 63;
  const int wave = tid >> 6;
  const int bid  = blockIdx.x;
  const int g    = bid >> 6;
  const int cblk = bid & 63;
  const int c0   = cblk * 8;

  #pragma unroll
  for (int i = 0; i < 8; ++i){
    uint4 z = make_uint4(0u,0u,0u,0u);
    *(uint4*)(AL + (i*256 + tid)*16) = z;
  }
  #pragma unroll
  for (int i = 0; i < 16; ++i){
    int f4  = i*256 + tid;
    int rl  = f4 >> 7;
    int k16 = f4 & 127;
    int q = rl >> 3, jj = rl & 7;
    int rowg = q*512 + c0 + jj;
    int ku0 = k16*4;
    uint4 v;
    if (ku0 < 256) v = *(const uint4*)((const uint32_t*)what + (size_t)rowg*256 + ku0);
    else           v = *(const uint4*)((const uint32_t*)uhat + (size_t)rowg*256 + (ku0-256));
    *(uint4*)(WU + rl*2048 + ((k16*16) ^ ((rl&7)<<4))) = v;
  }

  const int tb = tid >> 3;
  const int j  = tid & 7;
  float bsv[4];
  #pragma unroll
  for (int q = 0; q < 4; ++q) bsv[q] = bias[q*512 + c0 + j];
  float cst = 0.0f;

  uint32_t xr[16];
  auto prefx = [&](int t){
    #pragma unroll
    for (int i = 0; i < 8; ++i){
      int f4 = i*256 + tid;
      int rl = f4 >> 7;
      int kc = (f4 & 127)*4;
      float4 v = *(const float4*)(x + ((size_t)t*64 + g*16 + rl)*512 + kc);
      xr[2*i]   = (uint32_t)f2bf(v.x) | ((uint32_t)f2bf(v.y) << 16);
      xr[2*i+1] = (uint32_t)f2bf(v.z) | ((uint32_t)f2bf(v.w) << 16);
    }
  };
  auto writex = [&](){
    #pragma unroll
    for (int i = 0; i < 8; ++i){
      int f4 = i*256 + tid;
      int rl = f4 >> 7;
      int kb = (f4 & 127)*8;
      uint2 w; w.x = xr[2*i]; w.y = xr[2*i+1];
      *(uint2*)(AL + rl*2048 + (kb ^ ((rl&7)<<4))) = w;
    }
  };

  __syncthreads();
  prefx(0);
  writex();
  __syncthreads();

  const int arow = lane & 15;
  const int aswz = (arow & 7) << 4;
  const int q16  = (lane >> 4) << 4;

  for (int t = 0; t < T_STEPS; ++t){
    floatx4 a0 = (floatx4){0.f,0.f,0.f,0.f};
    floatx4 a1 = (floatx4){0.f,0.f,0.f,0.f};
    #pragma unroll
    for (int kt = 0; kt < 8; ++kt){
      int kb = wave*512 + kt*64 + q16;
      short8 av = *(const short8*)(AL + arow*2048 + (kb ^ aswz));
      short8 b0 = *(const short8*)(WU + arow*2048 + (kb ^ aswz));
      short8 b1 = *(const short8*)(WU + (16+arow)*2048 + (kb ^ aswz));
      a0 = __builtin_amdgcn_mfma_f32_16x16x32_bf16(av, b0, a0, 0,0,0);
      a1 = __builtin_amdgcn_mfma_f32_16x16x32_bf16(av, b1, a1, 0,0,0);
    }
    {
      int m0 = (lane >> 4) * 4;
      int n  = lane & 15;
      #pragma unroll
      for (int r = 0; r < 4; ++r){
        GP[(wave*16 + m0 + r)*36 + n]      = a0[r];
        GP[(wave*16 + m0 + r)*36 + n + 16] = a1[r];
      }
    }
    __syncthreads();

    if (tid < 128){
      float pre[4];
      #pragma unroll
      for (int q = 0; q < 4; ++q){
        float s = bsv[q];
        #pragma unroll
        for (int w = 0; w < 4; ++w) s += GP[(w*16 + tb)*36 + q*8 + j];
        pre[q] = s;
      }
      float iv = sigf(pre[0]);
      float fv = sigf(pre[1]);
      float gv = tanhf(pre[2]);
      float ov = sigf(pre[3]);
      cst = fv*cst + iv*gv;
      float hv = ov * tanhf(cst);
      out[((size_t)t*64 + g*16 + tb)*512 + c0 + j] = hv;
      hex[(size_t)(t&1)*32768 + (size_t)(g*16 + tb)*512 + c0 + j] = f2bf(hv);
    }

    int tn = (t+1 < T_STEPS) ? (t+1) : (T_STEPS-1);
    prefx(tn);

    __threadfence();
    grid.sync();

    {
      const uint32_t* hb = (const uint32_t*)hex + (size_t)(t&1)*16384;
      #pragma unroll
      for (int i = 0; i < 4; ++i){
        int f4 = i*256 + tid;
        int rl = f4 >> 6;
        int kp = (f4 & 63)*4;
        uint4 v = *(const uint4*)(hb + (size_t)(g*16 + rl)*256 + kp);
        *(uint4*)(AL + rl*2048 + ((1024 + kp*4) ^ ((rl&7)<<4))) = v;
      }
    }
    writex();
    __syncthreads();
  }
}

extern "C" void kernel_launch(void* const* d_in, const int* in_sizes, int n_in,
                              void* d_out, int out_size, void* d_ws, size_t ws_size,
                              hipStream_t stream) {
  (void)in_sizes; (void)n_in; (void)out_size;
  const float* x    = (const float*)d_in[0];
  const float* W    = (const float*)d_in[1];
  const float* U    = (const float*)d_in[2];
  const float* bias = (const float*)d_in[3];
  const float* la   = (const float*)d_in[4];
  float* out = (float*)d_out;
  char*  ws  = (char*)d_ws;

  uint16_t* hex  = (uint16_t*)(ws + OFF_HEX);
  uint16_t* what = (uint16_t*)(ws + OFF_WHAT);
  uint16_t* uhat = (uint16_t*)(ws + OFF_UHAT);
  uint16_t* xwp  = (uint16_t*)(ws + OFF_XW);

  const bool big = (ws_size >= WS_NEED_BIG);

  hipFuncSetAttribute((const void*)lstm_rec64,
                      hipFuncAttributeMaxDynamicSharedMemorySize, SMEM_REC64);
  hipFuncSetAttribute((const void*)lstm_fused,
                      hipFuncAttributeMaxDynamicSharedMemorySize, SMEM_FUSED);

  prep_weights<<<2048, 512, 0, stream>>>(W, U, la, what, uhat);

  if (big){
    gemm_xw<<<dim3(1000,16), 256, 0, stream>>>(x, what, xwp);
    void* args[] = { (void*)&uhat, (void*)&bias, (void*)&xwp,
                     (void*)&hex, (void*)&out };
    hipLaunchCooperativeKernel((const void*)lstm_rec64, dim3(64), dim3(256),
                               args, SMEM_REC64, stream);
  } else {
    void* args[] = { (void*)&what, (void*)&uhat, (void*)&bias,
                     (void*)&x, (void*)&hex, (void*)&out };
    hipLaunchCooperativeKernel((const void*)lstm_fused, dim3(256), dim3(256),
                               args, SMEM_FUSED, stream);
  }
}